// Round 11
// baseline (690.978 us; speedup 1.0000x reference)
//
#include <hip/hip_runtime.h>

#define NN 50000
#define EE 600000
#define HH 128
#define EDD 16
#define BB 256
#define LL 5
#define NN16 (NN * 16)
#define NSHADOW 8
#define GN 782  // (NN+63)/64

typedef float f32x4 __attribute__((ext_vector_type(4)));
typedef _Float16 f16x4 __attribute__((ext_vector_type(4)));
typedef _Float16 f16x8 __attribute__((ext_vector_type(8)));

// ---------------- all weight prep in one kernel ----------------
__global__ __launch_bounds__(256) void wprep_all_k(
    const float* __restrict__ W0, const float* __restrict__ W1, const float* __restrict__ W2,
    _Float16* __restrict__ H0, _Float16* __restrict__ L0,
    _Float16* __restrict__ H1, _Float16* __restrict__ L1,
    _Float16* __restrict__ H2, _Float16* __restrict__ L2,
    const float* __restrict__ eW, const float* __restrict__ eb, const float* __restrict__ nb,
    _Float16* __restrict__ BXh, _Float16* __restrict__ BXl)
{
    int idx = blockIdx.x * 256 + threadIdx.x;
    if (idx < 3 * 81920) {
        int seg = idx / 81920, r = idx - seg * 81920;
        const float* W = (seg == 0) ? W0 : (seg == 1) ? W1 : W2;
        _Float16* Wh = (seg == 0) ? H0 : (seg == 1) ? H1 : H2;
        _Float16* Wl = (seg == 0) ? L0 : (seg == 1) ? L1 : L2;
        int mat = r >> 14;
        int rr = r & 16383;
        int j = rr & 7, lane = (rr >> 3) & 63, ks = (rr >> 9) & 3, ntw = (rr >> 11) & 7;
        int lm = lane & 15, quad = lane >> 4;
        int n = (ntw >> 1) * 32 + (ntw & 1) * 16 + lm;
        int k = ks * 32 + quad * 8 + j;
        float w = W[(mat << 14) + (k << 7) + n];
        _Float16 h = (_Float16)w;
        Wh[r] = h;
        Wl[r] = (_Float16)(w - (float)h);
    } else {
        int i2 = idx - 3 * 81920;
        if (i2 >= 5 * 8192) return;
        int j = i2 & 7, lane = (i2 >> 3) & 63, ks = (i2 >> 9) & 1, ntw = (i2 >> 10) & 7, l = i2 >> 13;
        int lm = lane & 15, quad = lane >> 4;
        int n = (ntw >> 1) * 32 + (ntw & 1) * 16 + lm;
        int k = ks * 32 + quad * 8 + j;
        float v = 0.f;
        if (k < 16) v = eW[((size_t)l * 16 + k) * 128 + n];
        else if (k < 32) v = eW[((size_t)l * 16 + (k - 16)) * 128 + n];
        else if (k == 32) v = eb[l * 128 + n] + nb[l * 128 + n];
        _Float16 h = (_Float16)v;
        BXh[i2] = h;
        BXl[i2] = (_Float16)(v - (float)h);
    }
}

// ---------------- misc one-time: x->fp16, vn init, vn16 zero, pooled8 zero ----------------
__global__ __launch_bounds__(256) void misc_k(const float* __restrict__ x, _Float16* __restrict__ X0,
    const float* __restrict__ vninit, float* __restrict__ vn, _Float16* __restrict__ vn16,
    float* __restrict__ pooled8)
{
    int i = blockIdx.x * 256 + threadIdx.x;
    if (i < NN * 32) {
        float4 v = ((const float4*)x)[i];
        f16x4 o;
        o[0] = (_Float16)v.x; o[1] = (_Float16)v.y; o[2] = (_Float16)v.z; o[3] = (_Float16)v.w;
        ((f16x4*)X0)[i] = o;
    } else {
        int k = i - NN * 32;
        if (k < NSHADOW * BB * HH) pooled8[k] = 0.f;
        if (k < BB * HH) { vn[k] = vninit[k & 127]; vn16[k] = (_Float16)0; }
    }
}

// ---------------- shared GEMM helpers (r4) ----------------
__device__ __forceinline__ void mfma_stage16(
    const _Float16* __restrict__ As,
    const _Float16* __restrict__ Wh, const _Float16* __restrict__ Wl,
    int wn, int lm, int quad, int lane, f32x4 acc[4][2])
{
    f16x8 Bh[2][4], Bl[2][4];
#pragma unroll
    for (int nt = 0; nt < 2; ++nt)
#pragma unroll
        for (int ks = 0; ks < 4; ++ks) {
            int fi = ((((wn * 2 + nt) * 4) + ks) * 64 + lane) * 8;
            Bh[nt][ks] = *(const f16x8*)(Wh + fi);
            Bl[nt][ks] = *(const f16x8*)(Wl + fi);
        }
#pragma unroll
    for (int ks = 0; ks < 4; ++ks) {
        f16x8 a[4];
#pragma unroll
        for (int mt = 0; mt < 4; ++mt) {
            int off = (mt * 16 + lm) * 136 + ks * 32 + quad * 8;
            a[mt] = *(const f16x8*)(As + off);
        }
#pragma unroll
        for (int mt = 0; mt < 4; ++mt)
#pragma unroll
            for (int nt = 0; nt < 2; ++nt) {
                acc[mt][nt] = __builtin_amdgcn_mfma_f32_16x16x32_f16(a[mt], Bh[nt][ks], acc[mt][nt], 0, 0, 0);
                acc[mt][nt] = __builtin_amdgcn_mfma_f32_16x16x32_f16(a[mt], Bl[nt][ks], acc[mt][nt], 0, 0, 0);
            }
    }
}

__device__ __forceinline__ void store_f16(const _Float16* __restrict__ Fo,
    _Float16* __restrict__ out, int M, int brow, int tid)
{
    const int r = tid >> 2, cg = tid & 3;
    const int grow = brow + r;
    if (grow >= M) return;
    const f16x8* src = (const f16x8*)(Fo + r * 136 + cg * 32);
    f16x8* dst = (f16x8*)(out + (size_t)grow * 128 + cg * 32);
#pragma unroll
    for (int i = 0; i < 4; ++i) dst[i] = src[i];
}

// ---------------- fused layer kernel (r4 body; Cfrag replaced by L2-hot vn16 second-loop gather) ----------------
__global__ __launch_bounds__(256) void layer_k(
    const _Float16* __restrict__ Xin,
    const _Float16* __restrict__ Afix,          // padded to GN*64 rows, pad rows zero
    const _Float16* __restrict__ vn16, int usevn,
    const int* __restrict__ rowstart, const unsigned int* __restrict__ csrc,  // src | (g<<16)
    const _Float16* __restrict__ WNh, const _Float16* __restrict__ WNl,
    const _Float16* __restrict__ BXh, const _Float16* __restrict__ BXl,
    const _Float16* __restrict__ W1h, const _Float16* __restrict__ W1l, const float* __restrict__ b1,
    const _Float16* __restrict__ W2h, const _Float16* __restrict__ W2l, const float* __restrict__ b2,
    _Float16* __restrict__ Xout, float* __restrict__ pooled8,
    const int* __restrict__ batch, int M)
{
    __shared__ __align__(16) _Float16 bufA[64 * 136];   // X gather-sum, then MLP ping-pong
    __shared__ __align__(16) _Float16 bufB[64 * 136];   // VnSum, then MLP ping-pong
    const int tid = threadIdx.x, brow = blockIdx.x * 64;

    const int wv = tid >> 6, grp = (tid >> 4) & 3, li = tid & 15;
    const f16x8* X8 = (const f16x8*)Xin;

    // ---- gather phase 1 (r4 exact): bufA[node] = fp16( sum X[src] )
    for (int j = 0; j < 4; ++j) {
        int rnode = wv * 16 + grp * 4 + j;
        int node = brow + rnode;
        f16x8 o = (f16x8)(_Float16)0;
        if (node < M) {
            int s = rowstart[node], e = rowstart[node + 1];
            float ax[8];
#pragma unroll
            for (int k = 0; k < 8; ++k) ax[k] = 0.f;
            int p = s;
            for (; p + 4 <= e; p += 4) {
                int s0 = csrc[p] & 0xffff, s1 = csrc[p + 1] & 0xffff,
                    s2 = csrc[p + 2] & 0xffff, s3 = csrc[p + 3] & 0xffff;
                f16x8 x0 = X8[(size_t)s0 * 16 + li];
                f16x8 x1 = X8[(size_t)s1 * 16 + li];
                f16x8 x2 = X8[(size_t)s2 * 16 + li];
                f16x8 x3 = X8[(size_t)s3 * 16 + li];
#pragma unroll
                for (int k = 0; k < 8; ++k)
                    ax[k] += ((float)x0[k] + (float)x1[k]) + ((float)x2[k] + (float)x3[k]);
            }
            for (; p < e; ++p) {
                f16x8 x0 = X8[(size_t)(csrc[p] & 0xffff) * 16 + li];
#pragma unroll
                for (int k = 0; k < 8; ++k) ax[k] += (float)x0[k];
            }
#pragma unroll
            for (int k = 0; k < 8; ++k) o[k] = (_Float16)ax[k];
        }
        *(f16x8*)(bufA + rnode * 136 + li * 8) = o;
    }

    // ---- gather phase 2 (separate loop; vn16 is a 64KB L2-resident table -> ~zero FETCH)
    if (usevn) {
        const f16x8* V8 = (const f16x8*)vn16;
        for (int j = 0; j < 4; ++j) {
            int rnode = wv * 16 + grp * 4 + j;
            int node = brow + rnode;
            f16x8 ov = (f16x8)(_Float16)0;
            if (node < M) {
                int s = rowstart[node], e = rowstart[node + 1];
                float ev[8];
#pragma unroll
                for (int k = 0; k < 8; ++k) ev[k] = 0.f;
                int p = s;
                for (; p + 4 <= e; p += 4) {
                    unsigned g0 = csrc[p] >> 16, g1 = csrc[p + 1] >> 16,
                             g2 = csrc[p + 2] >> 16, g3 = csrc[p + 3] >> 16;
                    f16x8 v0 = V8[g0 * 16 + li];
                    f16x8 v1 = V8[g1 * 16 + li];
                    f16x8 v2 = V8[g2 * 16 + li];
                    f16x8 v3 = V8[g3 * 16 + li];
#pragma unroll
                    for (int k = 0; k < 8; ++k)
                        ev[k] += ((float)v0[k] + (float)v1[k]) + ((float)v2[k] + (float)v3[k]);
                }
                for (; p < e; ++p) {
                    f16x8 v0 = V8[(csrc[p] >> 16) * 16 + li];
#pragma unroll
                    for (int k = 0; k < 8; ++k) ev[k] += (float)v0[k];
                }
#pragma unroll
                for (int k = 0; k < 8; ++k) ov[k] = (_Float16)ev[k];
            }
            *(f16x8*)(bufB + rnode * 136 + li * 8) = ov;
        }
    }
    __syncthreads();

    const int lane = tid & 63, wn = tid >> 6, lm = lane & 15, quad = lane >> 4;
    const int colb = wn * 32 + lm;

    f32x4 acc[4][2];
#pragma unroll
    for (int mt = 0; mt < 4; ++mt) { acc[mt][0] = (f32x4)(0.f); acc[mt][1] = (f32x4)(0.f); }

    // K=64: [aggE_hi|aggE_lo|deg] @ [eW;eW;eb+nb]  (A-frags direct from padded global Afix, 8KB/block)
#pragma unroll
    for (int ksf = 0; ksf < 2; ++ksf) {
        f16x8 Bh[2], Bl[2];
#pragma unroll
        for (int nt = 0; nt < 2; ++nt) {
            int fi = (((wn * 2 + nt) * 2 + ksf) * 64 + lane) * 8;
            Bh[nt] = *(const f16x8*)(BXh + fi);
            Bl[nt] = *(const f16x8*)(BXl + fi);
        }
#pragma unroll
        for (int mt = 0; mt < 4; ++mt) {
            f16x8 a = *(const f16x8*)(Afix + (size_t)(brow + mt * 16 + lm) * 64 + ksf * 32 + quad * 8);
#pragma unroll
            for (int nt = 0; nt < 2; ++nt) {
                acc[mt][nt] = __builtin_amdgcn_mfma_f32_16x16x32_f16(a, Bh[nt], acc[mt][nt], 0, 0, 0);
                acc[mt][nt] = __builtin_amdgcn_mfma_f32_16x16x32_f16(a, Bl[nt], acc[mt][nt], 0, 0, 0);
            }
        }
    }

    // K=128: AggX @ nW
    mfma_stage16(bufA, WNh, WNl, wn, lm, quad, lane, acc);
    __syncthreads();

    // epilogue 1 (no relu; bias terms already inside GEMM): agg = acc (+ VnSum) -> bufA
    if (usevn) {
#pragma unroll
        for (int mt = 0; mt < 4; ++mt) {
#pragma unroll
            for (int r = 0; r < 4; ++r) {
                int trow = mt * 16 + quad * 4 + r;
                bufA[trow * 136 + colb]      = (_Float16)(acc[mt][0][r] + (float)bufB[trow * 136 + colb]);
                bufA[trow * 136 + colb + 16] = (_Float16)(acc[mt][1][r] + (float)bufB[trow * 136 + colb + 16]);
            }
        }
    } else {
#pragma unroll
        for (int mt = 0; mt < 4; ++mt) {
#pragma unroll
            for (int r = 0; r < 4; ++r) {
                int trow = mt * 16 + quad * 4 + r;
                bufA[trow * 136 + colb]      = (_Float16)acc[mt][0][r];
                bufA[trow * 136 + colb + 16] = (_Float16)acc[mt][1][r];
            }
        }
    }
    __syncthreads();

#pragma unroll
    for (int mt = 0; mt < 4; ++mt) { acc[mt][0] = (f32x4)(0.f); acc[mt][1] = (f32x4)(0.f); }
    mfma_stage16(bufA, W1h, W1l, wn, lm, quad, lane, acc);
    {
        const float c0 = b1[colb], c1 = b1[colb + 16];
#pragma unroll
        for (int mt = 0; mt < 4; ++mt) {
#pragma unroll
            for (int r = 0; r < 4; ++r) {
                int trow = mt * 16 + quad * 4 + r;
                bufB[trow * 136 + colb]      = (_Float16)fmaxf(acc[mt][0][r] + c0, 0.f);
                bufB[trow * 136 + colb + 16] = (_Float16)fmaxf(acc[mt][1][r] + c1, 0.f);
            }
        }
    }
    __syncthreads();

#pragma unroll
    for (int mt = 0; mt < 4; ++mt) { acc[mt][0] = (f32x4)(0.f); acc[mt][1] = (f32x4)(0.f); }
    mfma_stage16(bufB, W2h, W2l, wn, lm, quad, lane, acc);
    {
        const float d0 = b2[colb], d1 = b2[colb + 16];
#pragma unroll
        for (int mt = 0; mt < 4; ++mt) {
#pragma unroll
            for (int r = 0; r < 4; ++r) {
                int trow = mt * 16 + quad * 4 + r;
                bufA[trow * 136 + colb]      = (_Float16)fmaxf(acc[mt][0][r] + d0, 0.f);
                bufA[trow * 136 + colb + 16] = (_Float16)fmaxf(acc[mt][1][r] + d1, 0.f);
            }
        }
    }
    __syncthreads();
    store_f16(bufA, Xout, M, brow, tid);

    // pooled partial sums into shadow copy (blockIdx&7)
    {
        float* pooled = pooled8 + (size_t)(blockIdx.x & (NSHADOW - 1)) * (BB * HH);
        const int c = tid & 127, half = tid >> 7;
        const int row0 = half * 32;
        float sum = 0.f;
        int curg = -1;
        for (int r2 = 0; r2 < 32; ++r2) {
            int grow = brow + row0 + r2;
            if (grow >= M) break;
            int g = batch[grow];
            if (g != curg) {
                if (curg >= 0) atomicAdd(&pooled[curg * 128 + c], sum);
                curg = g; sum = 0.f;
            }
            sum += (float)bufA[(row0 + r2) * 136 + c];
        }
        if (curg >= 0) atomicAdd(&pooled[curg * 128 + c], sum);
    }
}

// ---------------- aggE + Afix merged: per-node eattr sum -> [hi|lo|deg|0] fp16 ----------------
__global__ __launch_bounds__(256) void aggfix_k(
    const float* __restrict__ eattr, const int* __restrict__ rowstart,
    const int* __restrict__ cedge, _Float16* __restrict__ Afix, int n)
{
    const int lane = threadIdx.x & 15;
    const int node = blockIdx.x * 16 + (threadIdx.x >> 4);
    if (node >= n) return;
    const int s = rowstart[node], e = rowstart[node + 1];
    float acc = 0.f;
    for (int p = s; p < e; ++p)
        acc += eattr[(size_t)cedge[p] * 16 + lane];
    _Float16 hi = (_Float16)acc;
    _Float16 lo = (_Float16)(acc - (float)hi);
    _Float16* A = Afix + (size_t)node * 64;
    A[lane] = hi;
    A[16 + lane] = lo;
    A[32 + lane] = (lane == 0) ? (_Float16)(float)(e - s) : (_Float16)0;
    A[48 + lane] = (_Float16)0;
}

// ---------------- degree histogram (4 shadows) ----------------
__global__ void histp_k(const int* __restrict__ idx, int n, int* __restrict__ cntp)
{
    int i = blockIdx.x * 256 + threadIdx.x;
    if (i < n) atomicAdd(&cntp[(blockIdx.x & 3) * NN16 + (idx[i] << 4)], 1);
}

// ---------------- VN update (writes linear fp16 vn16 table) ----------------
__global__ __launch_bounds__(128) void vn_update_k(
    float* __restrict__ pooled8, const int* __restrict__ gstart,
    const float* __restrict__ W0, const float* __restrict__ b0,
    const float* __restrict__ W1, const float* __restrict__ b1,
    float* __restrict__ vn, _Float16* __restrict__ vn16)
{
    __shared__ float p[128], q[128];
    const int g = blockIdx.x, t = threadIdx.x;
    float cnt = (float)(gstart[g + 1] - gstart[g]);
    if (cnt < 1.f) cnt = 1.f;
    float sum = 0.f;
#pragma unroll
    for (int s = 0; s < NSHADOW; ++s) {
        float* slot = pooled8 + (size_t)s * (BB * HH) + g * 128 + t;
        sum += *slot;
        *slot = 0.f;
    }
    p[t] = sum / cnt;
    __syncthreads();
    float a0 = b0[t];
    for (int k = 0; k < 128; ++k) a0 = fmaf(p[k], W0[k * 128 + t], a0);
    q[t] = fmaxf(a0, 0.f);
    __syncthreads();
    float a1 = b1[t];
    for (int k = 0; k < 128; ++k) a1 = fmaf(q[k], W1[k * 128 + t], a1);
    float nv = vn[g * 128 + t] + fmaxf(a1, 0.f);
    vn[g * 128 + t] = nv;
    vn16[g * 128 + t] = (_Float16)nv;
}

// ---------------- final classifier ----------------
__global__ __launch_bounds__(128) void fc_k(
    const float* __restrict__ pooled8, const int* __restrict__ gstart,
    const float* __restrict__ W, const float* __restrict__ b,
    float* __restrict__ out)
{
    __shared__ float p[128];
    const int g = blockIdx.x, t = threadIdx.x;
    float cnt = (float)(gstart[g + 1] - gstart[g]);
    if (cnt < 1.f) cnt = 1.f;
    float sum = 0.f;
#pragma unroll
    for (int s = 0; s < NSHADOW; ++s)
        sum += pooled8[(size_t)s * (BB * HH) + g * 128 + t];
    p[t] = sum / cnt;
    __syncthreads();
    float acc = b[t];
    for (int k = 0; k < 128; ++k) acc = fmaf(p[k], W[k * 128 + t], acc);
    out[g * 128 + t] = acc;
}

// ---------------- CSR build ----------------
__global__ void scan_deg_k(const int* __restrict__ degp, int n, int* __restrict__ out, int* __restrict__ bsum)
{
    __shared__ int s[256];
    int gid = blockIdx.x * 256 + threadIdx.x;
    int v = 0;
    if (gid < n) {
        int o = gid << 4;
        v = degp[o] + degp[NN16 + o] + degp[2 * NN16 + o] + degp[3 * NN16 + o];
    }
    s[threadIdx.x] = v;
    __syncthreads();
    for (int off = 1; off < 256; off <<= 1) {
        int t = (threadIdx.x >= off) ? s[threadIdx.x - off] : 0;
        __syncthreads();
        s[threadIdx.x] += t;
        __syncthreads();
    }
    int incl = s[threadIdx.x];
    if (gid < n) out[gid] = incl - v;
    if (bsum != nullptr && threadIdx.x == 255) bsum[blockIdx.x] = incl;
}

__global__ void scan_k(const int* __restrict__ in, int n, int* __restrict__ out,
                       const int* __restrict__ batch, int* __restrict__ gstart)
{
    __shared__ int s[256];
    int v = (threadIdx.x < n) ? in[threadIdx.x] : 0;
    s[threadIdx.x] = v;
    __syncthreads();
    for (int off = 1; off < 256; off <<= 1) {
        int t = (threadIdx.x >= off) ? s[threadIdx.x - off] : 0;
        __syncthreads();
        s[threadIdx.x] += t;
        __syncthreads();
    }
    if (threadIdx.x < n) out[threadIdx.x] = s[threadIdx.x] - v;
    {
        int b = threadIdx.x;
        int lo = 0, hi = NN;
        while (lo < hi) {
            int mid = (lo + hi) >> 1;
            if (batch[mid] < b) lo = mid + 1; else hi = mid;
        }
        gstart[b] = lo;
        if (threadIdx.x == 0) gstart[BB] = NN;
    }
}

__global__ void addoff_k(int* __restrict__ data, const int* __restrict__ boff,
                         int* __restrict__ cursorp, int n, int total)
{
    int i = blockIdx.x * 256 + threadIdx.x;
    if (i < n) {
        int v = data[i] + boff[blockIdx.x];
        data[i] = v;
        cursorp[i << 4] = v;
    }
    if (i == 0) data[n] = total;
}

// fill: pack src (16b) | graph-of-src (upper bits) into csrc; edge id into cedge
__global__ void fill_k(const int* __restrict__ dst, const int* __restrict__ src, int n,
                       const int* __restrict__ batch,
                       int* __restrict__ cursorp, unsigned int* __restrict__ csrc,
                       int* __restrict__ cedge)
{
    int e = blockIdx.x * 256 + threadIdx.x;
    if (e < n) {
        int sv = src[e];
        unsigned g = (unsigned)batch[sv];
        int slot = atomicAdd(&cursorp[dst[e] << 4], 1);
        csrc[slot] = (unsigned)sv | (g << 16);
        cedge[slot] = e;
    }
}

// ---------------- Launch ----------------
extern "C" void kernel_launch(void* const* d_in, const int* in_sizes, int n_in,
                              void* d_out, int out_size, void* d_ws, size_t ws_size,
                              hipStream_t stream)
{
    (void)in_sizes; (void)n_in; (void)out_size; (void)ws_size;
    const float* x       = (const float*)d_in[0];
    const float* eattr   = (const float*)d_in[1];
    const float* node_W  = (const float*)d_in[2];
    const float* node_b  = (const float*)d_in[3];
    const float* edge_W  = (const float*)d_in[4];
    const float* edge_b  = (const float*)d_in[5];
    const float* mlp1_W  = (const float*)d_in[6];
    const float* mlp1_b  = (const float*)d_in[7];
    const float* mlp2_W  = (const float*)d_in[8];
    const float* mlp2_b  = (const float*)d_in[9];
    const float* vn_w0   = (const float*)d_in[10];
    const float* vn_b0   = (const float*)d_in[11];
    const float* vn_w1   = (const float*)d_in[12];
    const float* vn_b1   = (const float*)d_in[13];
    const float* fc_W    = (const float*)d_in[14];
    const float* fc_b    = (const float*)d_in[15];
    const float* vn_init = (const float*)d_in[16];
    const int*   eidx    = (const int*)d_in[17];
    const int*   batch   = (const int*)d_in[18];
    const int* srcv = eidx;
    const int* dstv = eidx + EE;

    char* wp = (char*)d_ws;
    auto alloc = [&](size_t bytes) -> void* {
        void* p = (void*)wp;
        wp += (bytes + 255) & ~(size_t)255;
        return p;
    };
    // zero-init region: degp | Afix (padded) contiguous -> one memset (19.2 MB)
    int* degp       = (int*)alloc((size_t)4 * NN16 * 4);               // 12.8 MB
    _Float16* Afix  = (_Float16*)alloc((size_t)GN * 64 * 64 * 2);      // 6.4 MB
    const size_t zero_bytes = (size_t)4 * NN16 * 4 + (size_t)GN * 64 * 64 * 2;

    _Float16* X0   = (_Float16*)alloc((size_t)NN * HH * 2);
    _Float16* X1   = (_Float16*)alloc((size_t)NN * HH * 2);
    _Float16* X2   = (_Float16*)alloc((size_t)NN * HH * 2);
    float* vn      = (float*)alloc((size_t)BB * HH * 4);
    _Float16* vn16 = (_Float16*)alloc((size_t)BB * HH * 2);
    float* pooled8 = (float*)alloc((size_t)NSHADOW * BB * HH * 4);
    int* rowstart  = (int*)alloc((size_t)(NN + 1) * 4);
    int* cursorp   = (int*)alloc((size_t)NN16 * 4);
    unsigned int* csrc = (unsigned int*)alloc((size_t)EE * 4);
    int* cedge     = (int*)alloc((size_t)EE * 4);
    int* bsum      = (int*)alloc(256 * 4);
    int* boff      = (int*)alloc(256 * 4);
    int* gstart    = (int*)alloc((size_t)(BB + 1) * 4);
    _Float16* WtN_h = (_Float16*)alloc((size_t)5 * 16384 * 2);
    _Float16* WtN_l = (_Float16*)alloc((size_t)5 * 16384 * 2);
    _Float16* Wt1_h = (_Float16*)alloc((size_t)5 * 16384 * 2);
    _Float16* Wt1_l = (_Float16*)alloc((size_t)5 * 16384 * 2);
    _Float16* Wt2_h = (_Float16*)alloc((size_t)5 * 16384 * 2);
    _Float16* Wt2_l = (_Float16*)alloc((size_t)5 * 16384 * 2);
    _Float16* BXh   = (_Float16*)alloc((size_t)5 * 8192 * 2);
    _Float16* BXl   = (_Float16*)alloc((size_t)5 * 8192 * 2);

    (void)hipMemsetAsync(degp, 0, zero_bytes, stream);

    histp_k<<<(EE + 255) / 256, 256, 0, stream>>>(dstv, EE, degp);

    const int NB1 = (NN + 255) / 256;
    scan_deg_k<<<NB1, 256, 0, stream>>>(degp, NN, rowstart, bsum);
    scan_k<<<1, 256, 0, stream>>>(bsum, NB1, boff, batch, gstart);
    addoff_k<<<NB1, 256, 0, stream>>>(rowstart, boff, cursorp, NN, EE);
    fill_k<<<(EE + 255) / 256, 256, 0, stream>>>(dstv, srcv, EE, batch, cursorp, csrc, cedge);
    aggfix_k<<<(NN + 15) / 16, 256, 0, stream>>>(eattr, rowstart, cedge, Afix, NN);

    misc_k<<<(NN * 32 + NSHADOW * BB * HH) / 256, 256, 0, stream>>>(x, X0, vn_init, vn, vn16, pooled8);
    wprep_all_k<<<(3 * 81920 + 5 * 8192) / 256, 256, 0, stream>>>(
        node_W, mlp1_W, mlp2_W, WtN_h, WtN_l, Wt1_h, Wt1_l, Wt2_h, Wt2_l,
        edge_W, edge_b, node_b, BXh, BXl);

    const _Float16* xin = X0;
    for (int l = 0; l < LL; ++l) {
        _Float16* xout = (l & 1) ? X2 : X1;
        layer_k<<<GN, 256, 0, stream>>>(xin, Afix, vn16, (l > 0) ? 1 : 0,
            rowstart, csrc,
            WtN_h + (size_t)l * 16384, WtN_l + (size_t)l * 16384,
            BXh + (size_t)l * 8192, BXl + (size_t)l * 8192,
            Wt1_h + (size_t)l * 16384, Wt1_l + (size_t)l * 16384, mlp1_b + (size_t)l * HH,
            Wt2_h + (size_t)l * 16384, Wt2_l + (size_t)l * 16384, mlp2_b + (size_t)l * HH,
            xout, pooled8, batch, NN);
        if (l < LL - 1)
            vn_update_k<<<BB, 128, 0, stream>>>(pooled8, gstart, vn_w0, vn_b0, vn_w1, vn_b1, vn, vn16);
        xin = xout;
    }
    fc_k<<<BB, 128, 0, stream>>>(pooled8, gstart, fc_W, fc_b, (float*)d_out);
}

// Round 12
// 649.165 us; speedup vs baseline: 1.0644x; 1.0644x over previous
//
#include <hip/hip_runtime.h>

#define NN 50000
#define EE 600000
#define HH 128
#define EDD 16
#define BB 256
#define LL 5
#define NN16 (NN * 16)
#define NSHADOW 8
#define GN 782  // (NN+63)/64

typedef float f32x4 __attribute__((ext_vector_type(4)));
typedef _Float16 f16x4 __attribute__((ext_vector_type(4)));
typedef _Float16 f16x8 __attribute__((ext_vector_type(8)));

// ---------------- one-time prep: x->fp16, vn/pooled init, all weight fragging ----------------
__global__ __launch_bounds__(256) void prep_all_k(
    const float* __restrict__ x, _Float16* __restrict__ X0,
    const float* __restrict__ vninit, float* __restrict__ vn, _Float16* __restrict__ vnB,
    float* __restrict__ pooled8,
    const float* __restrict__ W0, const float* __restrict__ W1, const float* __restrict__ W2,
    _Float16* __restrict__ H0, _Float16* __restrict__ L0,
    _Float16* __restrict__ H1, _Float16* __restrict__ L1,
    _Float16* __restrict__ H2, _Float16* __restrict__ L2,
    const float* __restrict__ eW, const float* __restrict__ eb, const float* __restrict__ nb,
    _Float16* __restrict__ BXh, _Float16* __restrict__ BXl)
{
    int i = blockIdx.x * 256 + threadIdx.x;
    if (i < NN * 32) {
        float4 v = ((const float4*)x)[i];
        f16x4 o;
        o[0] = (_Float16)v.x; o[1] = (_Float16)v.y; o[2] = (_Float16)v.z; o[3] = (_Float16)v.w;
        ((f16x4*)X0)[i] = o;
        return;
    }
    i -= NN * 32;
    if (i < NSHADOW * BB * HH) {
        pooled8[i] = 0.f;
        if (i < BB * HH) { vn[i] = vninit[i & 127]; vnB[i] = (_Float16)0; }
        return;
    }
    i -= NSHADOW * BB * HH;
    if (i < 3 * 81920) {
        int seg = i / 81920, r = i - seg * 81920;
        const float* W = (seg == 0) ? W0 : (seg == 1) ? W1 : W2;
        _Float16* Wh = (seg == 0) ? H0 : (seg == 1) ? H1 : H2;
        _Float16* Wl = (seg == 0) ? L0 : (seg == 1) ? L1 : L2;
        int mat = r >> 14;
        int rr = r & 16383;
        int j = rr & 7, lane = (rr >> 3) & 63, ks = (rr >> 9) & 3, ntw = (rr >> 11) & 7;
        int lm = lane & 15, quad = lane >> 4;
        int n = (ntw >> 1) * 32 + (ntw & 1) * 16 + lm;
        int k = ks * 32 + quad * 8 + j;
        float w = W[(mat << 14) + (k << 7) + n];
        _Float16 h = (_Float16)w;
        Wh[r] = h;
        Wl[r] = (_Float16)(w - (float)h);
        return;
    }
    i -= 3 * 81920;
    if (i < 5 * 8192) {
        int j = i & 7, lane = (i >> 3) & 63, ks = (i >> 9) & 1, ntw = (i >> 10) & 7, l = i >> 13;
        int lm = lane & 15, quad = lane >> 4;
        int n = (ntw >> 1) * 32 + (ntw & 1) * 16 + lm;
        int k = ks * 32 + quad * 8 + j;
        float v = 0.f;
        if (k < 16) v = eW[((size_t)l * 16 + k) * 128 + n];
        else if (k < 32) v = eW[((size_t)l * 16 + (k - 16)) * 128 + n];
        else if (k == 32) v = eb[l * 128 + n] + nb[l * 128 + n];
        _Float16 h = (_Float16)v;
        BXh[i] = h;
        BXl[i] = (_Float16)(v - (float)h);
    }
}

// ---------------- shared GEMM helpers (r4 verbatim) ----------------
__device__ __forceinline__ void mfma_stage16(
    const _Float16* __restrict__ As,
    const _Float16* __restrict__ Wh, const _Float16* __restrict__ Wl,
    int wn, int lm, int quad, int lane, f32x4 acc[4][2])
{
    f16x8 Bh[2][4], Bl[2][4];
#pragma unroll
    for (int nt = 0; nt < 2; ++nt)
#pragma unroll
        for (int ks = 0; ks < 4; ++ks) {
            int fi = ((((wn * 2 + nt) * 4) + ks) * 64 + lane) * 8;
            Bh[nt][ks] = *(const f16x8*)(Wh + fi);
            Bl[nt][ks] = *(const f16x8*)(Wl + fi);
        }
#pragma unroll
    for (int ks = 0; ks < 4; ++ks) {
        f16x8 a[4];
#pragma unroll
        for (int mt = 0; mt < 4; ++mt) {
            int off = (mt * 16 + lm) * 136 + ks * 32 + quad * 8;
            a[mt] = *(const f16x8*)(As + off);
        }
#pragma unroll
        for (int mt = 0; mt < 4; ++mt)
#pragma unroll
            for (int nt = 0; nt < 2; ++nt) {
                acc[mt][nt] = __builtin_amdgcn_mfma_f32_16x16x32_f16(a[mt], Bh[nt][ks], acc[mt][nt], 0, 0, 0);
                acc[mt][nt] = __builtin_amdgcn_mfma_f32_16x16x32_f16(a[mt], Bl[nt][ks], acc[mt][nt], 0, 0, 0);
            }
    }
}

__device__ __forceinline__ void store_f16(const _Float16* __restrict__ Fo,
    _Float16* __restrict__ out, int M, int brow, int tid)
{
    const int r = tid >> 2, cg = tid & 3;
    const int grow = brow + r;
    if (grow >= M) return;
    const f16x8* src = (const f16x8*)(Fo + r * 136 + cg * 32);
    f16x8* dst = (f16x8*)(out + (size_t)grow * 128 + cg * 32);
#pragma unroll
    for (int i = 0; i < 4; ++i) dst[i] = src[i];
}

// ---------------- fused layer kernel (r4 verbatim): gather + GEMM1(K=128 + K=64 Afix + K=256 C@vn) + MLP1 + MLP2 + pool ----------------
__global__ __launch_bounds__(256) void layer_k(
    const _Float16* __restrict__ Xin,
    const _Float16* __restrict__ Afix,
    const _Float16* __restrict__ Cfrag, const _Float16* __restrict__ vnB, int usevn,
    const int* __restrict__ rowstart, const int2* __restrict__ csr,
    const _Float16* __restrict__ WNh, const _Float16* __restrict__ WNl,
    const _Float16* __restrict__ BXh, const _Float16* __restrict__ BXl,
    const _Float16* __restrict__ W1h, const _Float16* __restrict__ W1l, const float* __restrict__ b1,
    const _Float16* __restrict__ W2h, const _Float16* __restrict__ W2l, const float* __restrict__ b2,
    _Float16* __restrict__ Xout, float* __restrict__ pooled8,
    const int* __restrict__ batch, int M)
{
    __shared__ __align__(16) _Float16 bufA[64 * 136];
    __shared__ __align__(16) _Float16 bufB[64 * 136];   // first 64*72 doubles as Afix stage
    const int tid = threadIdx.x, brow = blockIdx.x * 64;

    // stage Afix [64 x 64] fp16 at stride 72 into bufB
    {
        const int r = tid >> 2, cg = tid & 3;
        const int grow = brow + r;
        _Float16* p = bufB + r * 72 + cg * 16;
        if (grow < M) {
            const f16x8* s = (const f16x8*)(Afix + (size_t)grow * 64 + cg * 16);
            ((f16x8*)p)[0] = s[0]; ((f16x8*)p)[1] = s[1];
        } else {
            f16x8 z = (f16x8)(_Float16)0;
            ((f16x8*)p)[0] = z; ((f16x8*)p)[1] = z;
        }
    }

    // gather phase: bufA[node] = fp16( sum_{e: dst=node} Xin[src_e] )  (fp32 accum)
    {
        const int wv = tid >> 6, grp = (tid >> 4) & 3, li = tid & 15;
        const f16x8* X8 = (const f16x8*)Xin;
        for (int j = 0; j < 4; ++j) {
            int rnode = wv * 16 + grp * 4 + j;
            int node = brow + rnode;
            f16x8 o = (f16x8)(_Float16)0;
            if (node < M) {
                int s = rowstart[node], e = rowstart[node + 1];
                float ax[8];
#pragma unroll
                for (int k = 0; k < 8; ++k) ax[k] = 0.f;
                int p = s;
                for (; p + 4 <= e; p += 4) {
                    int s0 = csr[p].x, s1 = csr[p + 1].x, s2 = csr[p + 2].x, s3 = csr[p + 3].x;
                    f16x8 x0 = X8[(size_t)s0 * 16 + li];
                    f16x8 x1 = X8[(size_t)s1 * 16 + li];
                    f16x8 x2 = X8[(size_t)s2 * 16 + li];
                    f16x8 x3 = X8[(size_t)s3 * 16 + li];
#pragma unroll
                    for (int k = 0; k < 8; ++k)
                        ax[k] += ((float)x0[k] + (float)x1[k]) + ((float)x2[k] + (float)x3[k]);
                }
                for (; p < e; ++p) {
                    f16x8 x0 = X8[(size_t)csr[p].x * 16 + li];
#pragma unroll
                    for (int k = 0; k < 8; ++k) ax[k] += (float)x0[k];
                }
#pragma unroll
                for (int k = 0; k < 8; ++k) o[k] = (_Float16)ax[k];
            }
            *(f16x8*)(bufA + rnode * 136 + li * 8) = o;
        }
    }
    __syncthreads();

    const int lane = tid & 63, wn = tid >> 6, lm = lane & 15, quad = lane >> 4;
    const int colb = wn * 32 + lm;

    f32x4 acc[4][2];
#pragma unroll
    for (int mt = 0; mt < 4; ++mt) { acc[mt][0] = (f32x4)(0.f); acc[mt][1] = (f32x4)(0.f); }

    // K=64: [aggE_hi|aggE_lo|deg] @ [eW;eW;eb+nb] (B hi/lo)
#pragma unroll
    for (int ksf = 0; ksf < 2; ++ksf) {
        f16x8 Bh[2], Bl[2];
#pragma unroll
        for (int nt = 0; nt < 2; ++nt) {
            int fi = (((wn * 2 + nt) * 2 + ksf) * 64 + lane) * 8;
            Bh[nt] = *(const f16x8*)(BXh + fi);
            Bl[nt] = *(const f16x8*)(BXl + fi);
        }
#pragma unroll
        for (int mt = 0; mt < 4; ++mt) {
            f16x8 a = *(const f16x8*)(bufB + (mt * 16 + lm) * 72 + ksf * 32 + quad * 8);
#pragma unroll
            for (int nt = 0; nt < 2; ++nt) {
                acc[mt][nt] = __builtin_amdgcn_mfma_f32_16x16x32_f16(a, Bh[nt], acc[mt][nt], 0, 0, 0);
                acc[mt][nt] = __builtin_amdgcn_mfma_f32_16x16x32_f16(a, Bl[nt], acc[mt][nt], 0, 0, 0);
            }
        }
    }

    // K=256: C @ vn (counts exact fp16)
    if (usevn) {
        const _Float16* Cb = Cfrag + (size_t)blockIdx.x * 16384;
#pragma unroll
        for (int ks = 0; ks < 8; ++ks) {
            f16x8 bv[2];
#pragma unroll
            for (int nt = 0; nt < 2; ++nt)
                bv[nt] = *(const f16x8*)(vnB + (((ks * 8 + (wn * 2 + nt)) * 64 + lane) * 8));
#pragma unroll
            for (int mt = 0; mt < 4; ++mt) {
                f16x8 av = *(const f16x8*)(Cb + (((mt * 8 + ks) * 64 + lane) * 8));
                acc[mt][0] = __builtin_amdgcn_mfma_f32_16x16x32_f16(av, bv[0], acc[mt][0], 0, 0, 0);
                acc[mt][1] = __builtin_amdgcn_mfma_f32_16x16x32_f16(av, bv[1], acc[mt][1], 0, 0, 0);
            }
        }
    }

    // K=128: AggX @ nW
    mfma_stage16(bufA, WNh, WNl, wn, lm, quad, lane, acc);
    __syncthreads();

    // epilogue 1 (no relu; all bias terms already inside GEMM): agg -> bufA
#pragma unroll
    for (int mt = 0; mt < 4; ++mt) {
#pragma unroll
        for (int r = 0; r < 4; ++r) {
            int trow = mt * 16 + quad * 4 + r;
            bufA[trow * 136 + colb]      = (_Float16)acc[mt][0][r];
            bufA[trow * 136 + colb + 16] = (_Float16)acc[mt][1][r];
        }
    }
    __syncthreads();

#pragma unroll
    for (int mt = 0; mt < 4; ++mt) { acc[mt][0] = (f32x4)(0.f); acc[mt][1] = (f32x4)(0.f); }
    mfma_stage16(bufA, W1h, W1l, wn, lm, quad, lane, acc);
    {
        const float c0 = b1[colb], c1 = b1[colb + 16];
#pragma unroll
        for (int mt = 0; mt < 4; ++mt) {
#pragma unroll
            for (int r = 0; r < 4; ++r) {
                int trow = mt * 16 + quad * 4 + r;
                bufB[trow * 136 + colb]      = (_Float16)fmaxf(acc[mt][0][r] + c0, 0.f);
                bufB[trow * 136 + colb + 16] = (_Float16)fmaxf(acc[mt][1][r] + c1, 0.f);
            }
        }
    }
    __syncthreads();

#pragma unroll
    for (int mt = 0; mt < 4; ++mt) { acc[mt][0] = (f32x4)(0.f); acc[mt][1] = (f32x4)(0.f); }
    mfma_stage16(bufB, W2h, W2l, wn, lm, quad, lane, acc);
    {
        const float d0 = b2[colb], d1 = b2[colb + 16];
#pragma unroll
        for (int mt = 0; mt < 4; ++mt) {
#pragma unroll
            for (int r = 0; r < 4; ++r) {
                int trow = mt * 16 + quad * 4 + r;
                bufA[trow * 136 + colb]      = (_Float16)fmaxf(acc[mt][0][r] + d0, 0.f);
                bufA[trow * 136 + colb + 16] = (_Float16)fmaxf(acc[mt][1][r] + d1, 0.f);
            }
        }
    }
    __syncthreads();
    store_f16(bufA, Xout, M, brow, tid);

    // pooled partial sums into shadow copy (blockIdx&7)
    {
        float* pooled = pooled8 + (size_t)(blockIdx.x & (NSHADOW - 1)) * (BB * HH);
        const int c = tid & 127, half = tid >> 7;
        const int row0 = half * 32;
        float sum = 0.f;
        int curg = -1;
        for (int r2 = 0; r2 < 32; ++r2) {
            int grow = brow + row0 + r2;
            if (grow >= M) break;
            int g = batch[grow];
            if (g != curg) {
                if (curg >= 0) atomicAdd(&pooled[curg * 128 + c], sum);
                curg = g; sum = 0.f;
            }
            sum += (float)bufA[(row0 + r2) * 136 + c];
        }
        if (curg >= 0) atomicAdd(&pooled[curg * 128 + c], sum);
    }
}

// ---------------- aggE + Afix merged: per-node eattr sum -> [hi|lo|deg|0] fp16 ----------------
__global__ __launch_bounds__(256) void aggfix_k(
    const float* __restrict__ eattr, const int* __restrict__ rowstart,
    const int2* __restrict__ csr, _Float16* __restrict__ Afix, int n)
{
    const int lane = threadIdx.x & 15;
    const int node = blockIdx.x * 16 + (threadIdx.x >> 4);
    if (node >= n) return;
    const int s = rowstart[node], e = rowstart[node + 1];
    float acc = 0.f;
    for (int p = s; p < e; ++p)
        acc += eattr[(size_t)(csr[p].y & 0xFFFFF) * 16 + lane];
    _Float16 hi = (_Float16)acc;
    _Float16 lo = (_Float16)(acc - (float)hi);
    _Float16* A = Afix + (size_t)node * 64;
    A[lane] = hi;
    A[16 + lane] = lo;
    A[32 + lane] = (lane == 0) ? (_Float16)(float)(e - s) : (_Float16)0;
    A[48 + lane] = (_Float16)0;
}

// ---------------- Cfrag build per block in LDS (replaces global atomics + ccvt + memset) ----------------
__global__ __launch_bounds__(256) void cfrag_k(
    const int* __restrict__ rowstart, const int2* __restrict__ csr,
    _Float16* __restrict__ Cfrag, int n)
{
    __shared__ unsigned int cnt[64 * 128];  // [row][g>>1], two u16 counts per word
    __shared__ int rs[65];
    const int tid = threadIdx.x, brow = blockIdx.x * 64;
    for (int i = tid; i < 64 * 128; i += 256) cnt[i] = 0u;
    if (tid < 65) {
        int node = brow + tid;
        rs[tid] = rowstart[node <= n ? node : n];
    }
    __syncthreads();
    const int s = rs[0], e = rs[64];
    for (int p = s + tid; p < e; p += 256) {
        int g = csr[p].y >> 20;
        int lo = 0, hi = 63;
        while (lo < hi) {
            int mid = (lo + hi + 1) >> 1;
            if (rs[mid] <= p) lo = mid; else hi = mid - 1;
        }
        atomicAdd(&cnt[lo * 128 + (g >> 1)], 1u << ((g & 1) * 16));
    }
    __syncthreads();
    const size_t base = (size_t)blockIdx.x * 16384;
    for (int i = tid; i < 16384; i += 256) {
        int j = i & 7, lanef = (i >> 3) & 63, ks = (i >> 9) & 7, mt = i >> 12;
        int lm = lanef & 15, quad = lanef >> 4;
        int row = mt * 16 + lm;
        int g = ks * 32 + quad * 8 + j;
        unsigned int w = cnt[row * 128 + (g >> 1)];
        unsigned int c = (g & 1) ? (w >> 16) : (w & 0xffffu);
        Cfrag[base + i] = (_Float16)(float)c;
    }
}

// ---------------- degree histogram (4 shadows) ----------------
__global__ void histp_k(const int* __restrict__ idx, int n, int* __restrict__ cntp)
{
    int i = blockIdx.x * 256 + threadIdx.x;
    if (i < n) atomicAdd(&cntp[(blockIdx.x & 3) * NN16 + (idx[i] << 4)], 1);
}

// ---------------- VN update (writes frag-ordered vnB) ----------------
__global__ __launch_bounds__(128) void vn_update_k(
    float* __restrict__ pooled8, const int* __restrict__ gstart,
    const float* __restrict__ W0, const float* __restrict__ b0,
    const float* __restrict__ W1, const float* __restrict__ b1,
    float* __restrict__ vn, _Float16* __restrict__ vnB)
{
    __shared__ float p[128], q[128];
    const int g = blockIdx.x, t = threadIdx.x;
    float cnt = (float)(gstart[g + 1] - gstart[g]);
    if (cnt < 1.f) cnt = 1.f;
    float sum = 0.f;
#pragma unroll
    for (int s = 0; s < NSHADOW; ++s) {
        float* slot = pooled8 + (size_t)s * (BB * HH) + g * 128 + t;
        sum += *slot;
        *slot = 0.f;
    }
    p[t] = sum / cnt;
    __syncthreads();
    float a0 = b0[t];
    for (int k = 0; k < 128; ++k) a0 = fmaf(p[k], W0[k * 128 + t], a0);
    q[t] = fmaxf(a0, 0.f);
    __syncthreads();
    float a1 = b1[t];
    for (int k = 0; k < 128; ++k) a1 = fmaf(q[k], W1[k * 128 + t], a1);
    float nv = vn[g * 128 + t] + fmaxf(a1, 0.f);
    vn[g * 128 + t] = nv;
    {
        int ks = g >> 5, quad = (g >> 3) & 3, j = g & 7;
        int tt = ((t >> 5) << 1) | ((t >> 4) & 1);
        int lanev = quad * 16 + (t & 15);
        vnB[((ks * 8 + tt) * 64 + lanev) * 8 + j] = (_Float16)nv;
    }
}

// ---------------- final classifier ----------------
__global__ __launch_bounds__(128) void fc_k(
    const float* __restrict__ pooled8, const int* __restrict__ gstart,
    const float* __restrict__ W, const float* __restrict__ b,
    float* __restrict__ out)
{
    __shared__ float p[128];
    const int g = blockIdx.x, t = threadIdx.x;
    float cnt = (float)(gstart[g + 1] - gstart[g]);
    if (cnt < 1.f) cnt = 1.f;
    float sum = 0.f;
#pragma unroll
    for (int s = 0; s < NSHADOW; ++s)
        sum += pooled8[(size_t)s * (BB * HH) + g * 128 + t];
    p[t] = sum / cnt;
    __syncthreads();
    float acc = b[t];
    for (int k = 0; k < 128; ++k) acc = fmaf(p[k], W[k * 128 + t], acc);
    out[g * 128 + t] = acc;
}

// ---------------- CSR build ----------------
__global__ void scan_deg_k(const int* __restrict__ degp, int n, int* __restrict__ out, int* __restrict__ bsum)
{
    __shared__ int s[256];
    int gid = blockIdx.x * 256 + threadIdx.x;
    int v = 0;
    if (gid < n) {
        int o = gid << 4;
        v = degp[o] + degp[NN16 + o] + degp[2 * NN16 + o] + degp[3 * NN16 + o];
    }
    s[threadIdx.x] = v;
    __syncthreads();
    for (int off = 1; off < 256; off <<= 1) {
        int t = (threadIdx.x >= off) ? s[threadIdx.x - off] : 0;
        __syncthreads();
        s[threadIdx.x] += t;
        __syncthreads();
    }
    int incl = s[threadIdx.x];
    if (gid < n) out[gid] = incl - v;
    if (bsum != nullptr && threadIdx.x == 255) bsum[blockIdx.x] = incl;
}

// addoff + self-scan of bsum + cursor init + gstart (block 0) in one kernel
__global__ void addoff2_k(int* __restrict__ data, const int* __restrict__ bsum,
                          int* __restrict__ cursorp,
                          const int* __restrict__ batch, int* __restrict__ gstart,
                          int n, int total)
{
    __shared__ int s[256];
    const int t = threadIdx.x;
    s[t] = (t < (int)blockIdx.x) ? bsum[t] : 0;   // grid ≤ 256 blocks
    __syncthreads();
    for (int off = 1; off < 256; off <<= 1) {
        int v = (t >= off) ? s[t - off] : 0;
        __syncthreads();
        s[t] += v;
        __syncthreads();
    }
    const int boff = s[255];
    int i = blockIdx.x * 256 + t;
    if (i < n) {
        int v = data[i] + boff;
        data[i] = v;
        cursorp[i << 4] = v;
    }
    if (i == 0) data[n] = total;
    if (blockIdx.x == 0) {
        int b = t;
        int lo = 0, hi = NN;
        while (lo < hi) {
            int mid = (lo + hi) >> 1;
            if (batch[mid] < b) lo = mid + 1; else hi = mid;
        }
        gstart[b] = lo;
        if (t == 0) gstart[BB] = NN;
    }
}

// fill: csr.x = src, csr.y = edge | (graph-of-src << 20)
__global__ void fill_k(const int* __restrict__ dst, const int* __restrict__ src, int n,
                       const int* __restrict__ batch,
                       int* __restrict__ cursorp, int2* __restrict__ csr)
{
    int e = blockIdx.x * 256 + threadIdx.x;
    if (e < n) {
        int sv = src[e];
        int g = batch[sv];
        int slot = atomicAdd(&cursorp[dst[e] << 4], 1);
        int2 pr; pr.x = sv; pr.y = e | (g << 20);
        csr[slot] = pr;
    }
}

// ---------------- Launch ----------------
extern "C" void kernel_launch(void* const* d_in, const int* in_sizes, int n_in,
                              void* d_out, int out_size, void* d_ws, size_t ws_size,
                              hipStream_t stream)
{
    (void)in_sizes; (void)n_in; (void)out_size; (void)ws_size;
    const float* x       = (const float*)d_in[0];
    const float* eattr   = (const float*)d_in[1];
    const float* node_W  = (const float*)d_in[2];
    const float* node_b  = (const float*)d_in[3];
    const float* edge_W  = (const float*)d_in[4];
    const float* edge_b  = (const float*)d_in[5];
    const float* mlp1_W  = (const float*)d_in[6];
    const float* mlp1_b  = (const float*)d_in[7];
    const float* mlp2_W  = (const float*)d_in[8];
    const float* mlp2_b  = (const float*)d_in[9];
    const float* vn_w0   = (const float*)d_in[10];
    const float* vn_b0   = (const float*)d_in[11];
    const float* vn_w1   = (const float*)d_in[12];
    const float* vn_b1   = (const float*)d_in[13];
    const float* fc_W    = (const float*)d_in[14];
    const float* fc_b    = (const float*)d_in[15];
    const float* vn_init = (const float*)d_in[16];
    const int*   eidx    = (const int*)d_in[17];
    const int*   batch   = (const int*)d_in[18];
    const int* srcv = eidx;
    const int* dstv = eidx + EE;

    char* wp = (char*)d_ws;
    auto alloc = [&](size_t bytes) -> void* {
        void* p = (void*)wp;
        wp += (bytes + 255) & ~(size_t)255;
        return p;
    };
    int* degp       = (int*)alloc((size_t)4 * NN16 * 4);             // 12.8 MB (memset region)
    const size_t zero_bytes = (size_t)4 * NN16 * 4;
    _Float16* Cfrag = (_Float16*)alloc((size_t)GN * 16384 * 2);      // fully written by cfrag_k

    _Float16* X0   = (_Float16*)alloc((size_t)NN * HH * 2);
    _Float16* X1   = (_Float16*)alloc((size_t)NN * HH * 2);
    _Float16* X2   = (_Float16*)alloc((size_t)NN * HH * 2);
    _Float16* Afix = (_Float16*)alloc((size_t)NN * 64 * 2);
    float* vn      = (float*)alloc((size_t)BB * HH * 4);
    _Float16* vnB  = (_Float16*)alloc((size_t)BB * HH * 2);
    float* pooled8 = (float*)alloc((size_t)NSHADOW * BB * HH * 4);
    int* rowstart  = (int*)alloc((size_t)(NN + 1) * 4);
    int* cursorp   = (int*)alloc((size_t)NN16 * 4);
    int2* csr      = (int2*)alloc((size_t)EE * 8);
    int* bsum      = (int*)alloc(256 * 4);
    int* gstart    = (int*)alloc((size_t)(BB + 1) * 4);
    _Float16* WtN_h = (_Float16*)alloc((size_t)5 * 16384 * 2);
    _Float16* WtN_l = (_Float16*)alloc((size_t)5 * 16384 * 2);
    _Float16* Wt1_h = (_Float16*)alloc((size_t)5 * 16384 * 2);
    _Float16* Wt1_l = (_Float16*)alloc((size_t)5 * 16384 * 2);
    _Float16* Wt2_h = (_Float16*)alloc((size_t)5 * 16384 * 2);
    _Float16* Wt2_l = (_Float16*)alloc((size_t)5 * 16384 * 2);
    _Float16* BXh   = (_Float16*)alloc((size_t)5 * 8192 * 2);
    _Float16* BXl   = (_Float16*)alloc((size_t)5 * 8192 * 2);

    (void)hipMemsetAsync(degp, 0, zero_bytes, stream);

    histp_k<<<(EE + 255) / 256, 256, 0, stream>>>(dstv, EE, degp);

    const int NB1 = (NN + 255) / 256;  // 196 ≤ 256
    scan_deg_k<<<NB1, 256, 0, stream>>>(degp, NN, rowstart, bsum);
    addoff2_k<<<NB1, 256, 0, stream>>>(rowstart, bsum, cursorp, batch, gstart, NN, EE);
    fill_k<<<(EE + 255) / 256, 256, 0, stream>>>(dstv, srcv, EE, batch, cursorp, csr);
    aggfix_k<<<(NN + 15) / 16, 256, 0, stream>>>(eattr, rowstart, csr, Afix, NN);
    cfrag_k<<<GN, 256, 0, stream>>>(rowstart, csr, Cfrag, NN);

    const int PREP_TOTAL = NN * 32 + NSHADOW * BB * HH + 3 * 81920 + 5 * 8192;
    prep_all_k<<<(PREP_TOTAL + 255) / 256, 256, 0, stream>>>(
        x, X0, vn_init, vn, vnB, pooled8,
        node_W, mlp1_W, mlp2_W, WtN_h, WtN_l, Wt1_h, Wt1_l, Wt2_h, Wt2_l,
        edge_W, edge_b, node_b, BXh, BXl);

    const _Float16* xin = X0;
    for (int l = 0; l < LL; ++l) {
        _Float16* xout = (l & 1) ? X2 : X1;
        layer_k<<<GN, 256, 0, stream>>>(xin, Afix, Cfrag, vnB, (l > 0) ? 1 : 0,
            rowstart, csr,
            WtN_h + (size_t)l * 16384, WtN_l + (size_t)l * 16384,
            BXh + (size_t)l * 8192, BXl + (size_t)l * 8192,
            Wt1_h + (size_t)l * 16384, Wt1_l + (size_t)l * 16384, mlp1_b + (size_t)l * HH,
            Wt2_h + (size_t)l * 16384, Wt2_l + (size_t)l * 16384, mlp2_b + (size_t)l * HH,
            xout, pooled8, batch, NN);
        if (l < LL - 1)
            vn_update_k<<<BB, 128, 0, stream>>>(pooled8, gstart, vn_w0, vn_b0, vn_w1, vn_b1, vn, vnB);
        xin = xout;
    }
    fc_k<<<BB, 128, 0, stream>>>(pooled8, gstart, fc_W, fc_b, (float*)d_out);
}